// Round 14
// baseline (35124.155 us; speedup 1.0000x reference)
//
#include <hip/hip_runtime.h>
#include <hip/hip_fp16.h>
#include <cmath>

#define NN 68     // nodes
#define NT 136    // 2 threads per node (K-split), 3 waves
#define BW 72     // words per buffer: 2 chunks x 18 pairs x 2 (A,B interleaved)

typedef _Float16 h2 __attribute__((ext_vector_type(2)));
__device__ __forceinline__ h2 as_h2(unsigned u) {
    return __builtin_bit_cast(h2, u);
}

// lane XOR 1 within quad via DPP quad_perm [1,0,3,2] -- pure VALU, no LDS
__device__ __forceinline__ float dpp_xor1(float x) {
    return __int_as_float(
        __builtin_amdgcn_mov_dpp(__float_as_int(x), 0xB1, 0xF, 0xF, true));
}

#if __has_builtin(__builtin_amdgcn_exp2f)
#define FAST_EXP2(x) __builtin_amdgcn_exp2f(x)
#else
#define FAST_EXP2(x) exp2f(x)
#endif
#define FAST_RCP(x) __builtin_amdgcn_rcpf(x)

#if __has_builtin(__builtin_amdgcn_fdot2)
#define DOT2(c, e, acc) __builtin_amdgcn_fdot2(as_h2(c), as_h2(e), (acc), false)
#else
__device__ __forceinline__ float dot2_sw(unsigned c, unsigned e, float acc) {
    h2 ch = as_h2(c), eh = as_h2(e);
    acc = fmaf((float)ch.x, (float)eh.x, acc);
    return fmaf((float)ch.y, (float)eh.y, acc);
}
#define DOT2(c, e, acc) dot2_sw(c, e, acc)
#endif

__device__ __forceinline__ unsigned packh2(float a, float b) {
    __half2 h = __floats2half2_rn(a, b);   // RNE
    return *reinterpret_cast<unsigned*>(&h);
}

// ONE-TIME register pins (round-14 lever): the barrier asm's "memory"
// clobber invalidates every memory-derived value each superstep -- params
// reloads, inv_tau re-divides, C reloads. Laundering them through an empty
// asm ONCE (outside the loop) makes them opaque register values the
// clobber cannot touch. (R3: one-time C pin ~neutral; R6: IN-loop pins
// regress -- placement is everything.)
#define PINF(x) asm volatile("" : "+v"(x))
#define PINU4(q) asm volatile("" : "+v"(q.x), "+v"(q.y), "+v"(q.z), "+v"(q.w))

// Interleaved layout: word 2p = A-pair(k=2p), word 2p+1 = B-pair(k=2p).
#define MAC8(c, uA, uB)                          \
    a0 = DOT2(c.x, uA.x, a0); b0 = DOT2(c.x, uA.y, b0); \
    a1 = DOT2(c.y, uA.z, a1); b1 = DOT2(c.y, uA.w, b1); \
    a2 = DOT2(c.z, uB.x, a2); b2 = DOT2(c.z, uB.y, b2); \
    a3 = DOT2(c.w, uB.z, a3); b3 = DOT2(c.w, uB.w, b3);

// one Euler sub-step (R4-validated fast exp2/rcp math, hand-fma'd)
#define ELEM(Ein, Iin, CONN, Eout, Iout)                                      \
    {                                                                         \
        const float xE = fmaf(P5, (CONN),                                     \
                              fmaf(P1, (Ein), fmaf(-P2, (Iin), Pp)));         \
        const float Se = FAST_RCP(1.0f + FAST_EXP2(fmaf(kE2, xE, bE2))) - s0E;\
        const float xI = fmaf(P3, (Ein), -(P4 * (Iin)));                      \
        const float Si = FAST_RCP(1.0f + FAST_EXP2(fmaf(kI2, xI, bI2))) - s0I;\
        Eout = fmaf(fmaf(kE - (Ein), Se, -(Ein)), inv_te, (Ein));             \
        Iout = fmaf(fmaf(kI - (Iin), Si, -(Iin)), inv_ti, (Iin));             \
    }

// SUPERSTEP: steps T, T+1, ONE barrier, NO pre-barrier waitcnt (R13,
// validated bit-identical). Early En1 write ages the write before the race
// window. 9 ds_read_b128, 36 v_dot2.
#define SUPER(R, W, D1, D2)                                                   \
    {                                                                         \
        const uint4* vp_ = (const uint4*)&(R)[s * 36];                        \
        const uint4 u0 = vp_[0], u1 = vp_[1], u2 = vp_[2], u3 = vp_[3],       \
                    u4 = vp_[4], u5 = vp_[5], u6 = vp_[6], u7 = vp_[7],       \
                    u8 = vp_[8];                                              \
        float a0=0.f,a1=0.f,a2=0.f,a3=0.f,b0=0.f,b1=0.f,b2=0.f,b3=0.f;        \
        MAC8(c0, u0, u1) MAC8(c1, u2, u3)                                     \
        MAC8(c2, u4, u5) MAC8(c3, u6, u7)                                     \
        a0 = DOT2(c4x, u8.x, a0); b0 = DOT2(c4x, u8.y, b0);                   \
        a1 = DOT2(c4y, u8.z, a1); b1 = DOT2(c4y, u8.w, b1);                   \
        float pA = (a0 + a1) + (a2 + a3);                                     \
        float pB = (b0 + b1) + (b2 + b3);                                     \
        pA += dpp_xor1(pA);            /* both K-lanes: full dot */           \
        pB += dpp_xor1(pB);                                                   \
        float En1, In1, En2, In2;                                             \
        ELEM(E, I, pA, En1, In1)       /* step T */                           \
        *(__half*)((char*)(W) + wbA) = __float2half_rn(En1);  /* early */     \
        ELEM(En1, In1, pB, En2, In2)   /* step T+1 */                         \
        *(__half*)((char*)(W) + wbB) = __float2half_rn(En2);                  \
        D1 = En1 - In1; D2 = En2 - In2;                                       \
        E = En2; I = In2;                                                     \
        asm volatile("s_barrier" ::: "memory");                               \
    }

__global__ __launch_bounds__(NT, 1)
void nmm_kernel(const float* __restrict__ params,
                const float* __restrict__ Cjk,
                const float* __restrict__ y0,
                float* __restrict__ out,
                const int num_steps)
{
#pragma clang fp contract(off)
    const int tid = threadIdx.x;
    const int j   = tid >> 1;    // node 0..67
    const int s   = tid & 1;     // K-half 0/1

    // interleaved f16 (A,B) buffers, ping-ponged per superstep
    __shared__ __align__(16) unsigned Pb0[BW], Pb1[BW];

    const float tau_e = params[0], tau_i = params[1];
    float P1 = params[2], P2 = params[3], P3 = params[4];
    float P4 = params[5], P5 = params[6], Pp = params[7];
    float kE = params[8], kI = params[9];

    // literal-derived constants: compile-time folded, immune to the clobber
    const float LOG2E = 1.4426950408889634f;
    const float kE2 = -1.3f * LOG2E, bE2 = (1.3f * 4.0f) * LOG2E;
    const float kI2 = -2.0f * LOG2E, bI2 = (2.0f * 3.7f) * LOG2E;
    const float s0E = 1.0f / (1.0f + expf(5.2f));
    const float s0I = 1.0f / (1.0f + expf(7.4f));
    // runtime-derived: compute ONCE, then pin below
    float inv_te = 1.0f / tau_e, inv_ti = 1.0f / tau_i;

    // C row j, K-chunk s -> 18 half2 words (s=1: pairs 16,17 are zero pad)
    const float* crow = Cjk + j * NN;
    const int k0 = s * 36;
    auto cp = [&](int m) -> unsigned {
        const int k = k0 + 2 * m;
        return (k + 1 < NN) ? packh2(crow[k], crow[k + 1]) : 0u;
    };
    uint4 c0 = make_uint4(cp(0),  cp(1),  cp(2),  cp(3));
    uint4 c1 = make_uint4(cp(4),  cp(5),  cp(6),  cp(7));
    uint4 c2 = make_uint4(cp(8),  cp(9),  cp(10), cp(11));
    uint4 c3 = make_uint4(cp(12), cp(13), cp(14), cp(15));
    unsigned c4x = cp(16), c4y = cp(17);

    // init: reference steps 0 AND 1 both use C@E_0 -> A = B = E_0 pairs
    for (int idx = tid; idx < 2 * BW; idx += NT) {
        const int b  = (idx >= BW) ? 1 : 0;
        const int w  = idx - b * BW;
        const int si = w / 36, wl = w - si * 36, pl = wl >> 1;
        const int k  = si * 36 + 2 * pl;
        unsigned v = 0u;
        if (b == 0 && k + 1 < NN) v = packh2(y0[k], y0[k + 1]);
        (b ? Pb1 : Pb0)[w] = v;
    }

    // this node's write slots (byte offsets): A-word then B-word
    const int siW = (j >= 36) ? 1 : 0;
    const int kl  = j - siW * 36;
    const int wbA = (siW * 36 + 2 * (kl >> 1)) * 4 + (kl & 1) * 2;
    const int wbB = wbA + 4;

    float E = y0[j];
    float I = y0[NN + j];
    float* op = out + (size_t)j * (size_t)num_steps;

    // ---- ONE-TIME PINS: everything memory-derived that must stay resident
    PINF(P1); PINF(P2); PINF(P3); PINF(P4); PINF(P5); PINF(Pp);
    PINF(kE); PINF(kI); PINF(inv_te); PINF(inv_ti);
    PINU4(c0); PINU4(c1); PINU4(c2); PINU4(c3);
    asm volatile("" : "+v"(c4x), "+v"(c4y));
    asm volatile("" : "+v"(op));

    // init barrier keeps the full waitcnt (one-time cost)
    asm volatile("s_waitcnt lgkmcnt(0)\ns_barrier" ::: "memory");

    int t = 0;
    for (; t + 3 < num_steps; t += 4) {
        float d0, d1, d2, d3;
        SUPER(Pb0, Pb1, d0, d1)
        SUPER(Pb1, Pb0, d2, d3)
        if (s == 0) *(float4*)(op + t) = make_float4(d0, d1, d2, d3);
    }
    // generic tails (dead for num_steps % 4 == 0, kept for correctness)
    bool rb1 = false;
    if (t + 1 < num_steps) {
        float d0, d1;
        SUPER(Pb0, Pb1, d0, d1)
        if (s == 0) *(float2*)(op + t) = make_float2(d0, d1);
        t += 2; rb1 = true;
    }
    if (t < num_steps) {   // final odd step: conn = C @ A-halves (E_{t-1})
        const unsigned* R = rb1 ? Pb1 : Pb0;
        const uint4* vp_ = (const uint4*)&R[s * 36];
        const uint4 u0 = vp_[0], u1 = vp_[1], u2 = vp_[2], u3 = vp_[3],
                    u4 = vp_[4], u5 = vp_[5], u6 = vp_[6], u7 = vp_[7],
                    u8 = vp_[8];
        float a0 = 0.f, a1 = 0.f, a2 = 0.f, a3 = 0.f;
#define MACL(c, uA, uB)                     \
        a0 = DOT2(c.x, uA.x, a0);           \
        a1 = DOT2(c.y, uA.z, a1);           \
        a2 = DOT2(c.z, uB.x, a2);           \
        a3 = DOT2(c.w, uB.z, a3);
        MACL(c0, u0, u1) MACL(c1, u2, u3) MACL(c2, u4, u5) MACL(c3, u6, u7)
        a0 = DOT2(c4x, u8.x, a0);
        a1 = DOT2(c4y, u8.z, a1);
#undef MACL
        float pA = (a0 + a1) + (a2 + a3);
        pA += dpp_xor1(pA);
        float En1, In1;
        ELEM(E, I, pA, En1, In1)
        if (s == 0) op[t] = En1 - In1;
    }
}

extern "C" void kernel_launch(void* const* d_in, const int* in_sizes, int n_in,
                              void* d_out, int out_size, void* d_ws, size_t ws_size,
                              hipStream_t stream) {
    const float* params = (const float*)d_in[0];
    const float* Cjk    = (const float*)d_in[1];
    const float* y0     = (const float*)d_in[2];
    const int num_steps = out_size / NN;

    nmm_kernel<<<dim3(1), dim3(NT), 0, stream>>>(
        params, Cjk, y0, (float*)d_out, num_steps);
}

// Round 16
// 31172.653 us; speedup vs baseline: 1.1268x; 1.1268x over previous
//
#include <hip/hip_runtime.h>
#include <hip/hip_fp16.h>
#include <cmath>

#define NN 68     // nodes
#define NT 136    // 2 threads per node (K-split), 3 waves
#define BW 72     // words per buffer: 2 chunks x 18 pairs x 2 (A,B interleaved)

typedef _Float16 h2 __attribute__((ext_vector_type(2)));
__device__ __forceinline__ h2 as_h2(unsigned u) {
    return __builtin_bit_cast(h2, u);
}

// lane XOR 1 within quad via DPP quad_perm [1,0,3,2] -- pure VALU, no LDS
__device__ __forceinline__ float dpp_xor1(float x) {
    return __int_as_float(
        __builtin_amdgcn_mov_dpp(__float_as_int(x), 0xB1, 0xF, 0xF, true));
}

#if __has_builtin(__builtin_amdgcn_exp2f)
#define FAST_EXP2(x) __builtin_amdgcn_exp2f(x)
#else
#define FAST_EXP2(x) exp2f(x)
#endif
#define FAST_RCP(x) __builtin_amdgcn_rcpf(x)

#if __has_builtin(__builtin_amdgcn_fdot2)
#define DOT2(c, e, acc) __builtin_amdgcn_fdot2(as_h2(c), as_h2(e), (acc), false)
#else
__device__ __forceinline__ float dot2_sw(unsigned c, unsigned e, float acc) {
    h2 ch = as_h2(c), eh = as_h2(e);
    acc = fmaf((float)ch.x, (float)eh.x, acc);
    return fmaf((float)ch.y, (float)eh.y, acc);
}
#define DOT2(c, e, acc) dot2_sw(c, e, acc)
#endif

__device__ __forceinline__ unsigned packh2(float a, float b) {
    __half2 h = __floats2half2_rn(a, b);   // RNE
    return *reinterpret_cast<unsigned*>(&h);
}

// Interleaved layout: word 2p = A-pair(k=2p), word 2p+1 = B-pair(k=2p).
#define MAC8(c, uA, uB)                          \
    a0 = DOT2(c.x, uA.x, a0); b0 = DOT2(c.x, uA.y, b0); \
    a1 = DOT2(c.y, uA.z, a1); b1 = DOT2(c.y, uA.w, b1); \
    a2 = DOT2(c.z, uB.x, a2); b2 = DOT2(c.z, uB.y, b2); \
    a3 = DOT2(c.w, uB.z, a3); b3 = DOT2(c.w, uB.w, b3);

// one Euler sub-step (R4-validated fast exp2/rcp math, hand-fma'd)
#define ELEM(Ein, Iin, CONN, Eout, Iout)                                      \
    {                                                                         \
        const float xE = fmaf(P5, (CONN),                                     \
                              fmaf(P1, (Ein), fmaf(-P2, (Iin), Pp)));         \
        const float Se = FAST_RCP(1.0f + FAST_EXP2(fmaf(kE2, xE, bE2))) - s0E;\
        const float xI = fmaf(P3, (Ein), -(P4 * (Iin)));                      \
        const float Si = FAST_RCP(1.0f + FAST_EXP2(fmaf(kI2, xI, bI2))) - s0I;\
        Eout = fmaf(fmaf(kE - (Ein), Se, -(Ein)), inv_te, (Ein));             \
        Iout = fmaf(fmaf(kI - (Iin), Si, -(Iin)), inv_ti, (Iin));             \
    }

// SUPERSTEP: steps T, T+1, ONE barrier, NO pre-barrier waitcnt (R13,
// validated bit-identical across runs). Early En1 write ages the write
// before the race window. Write-split (R16): lane s=0 writes the A
// halfword, s=1 the B halfword -- same values, half the write issues.
#define SUPER(R, W, D1, D2)                                                   \
    {                                                                         \
        const uint4* vp_ = (const uint4*)&(R)[s * 36];                        \
        const uint4 u0 = vp_[0], u1 = vp_[1], u2 = vp_[2], u3 = vp_[3],       \
                    u4 = vp_[4], u5 = vp_[5], u6 = vp_[6], u7 = vp_[7],       \
                    u8 = vp_[8];                                              \
        float a0=0.f,a1=0.f,a2=0.f,a3=0.f,b0=0.f,b1=0.f,b2=0.f,b3=0.f;        \
        MAC8(c0, u0, u1) MAC8(c1, u2, u3)                                     \
        MAC8(c2, u4, u5) MAC8(c3, u6, u7)                                     \
        a0 = DOT2(c4x, u8.x, a0); b0 = DOT2(c4x, u8.y, b0);                   \
        a1 = DOT2(c4y, u8.z, a1); b1 = DOT2(c4y, u8.w, b1);                   \
        float pA = (a0 + a1) + (a2 + a3);                                     \
        float pB = (b0 + b1) + (b2 + b3);                                     \
        pA += dpp_xor1(pA);            /* both K-lanes: full dot */           \
        pB += dpp_xor1(pB);                                                   \
        float En1, In1, En2, In2;                                             \
        ELEM(E, I, pA, En1, In1)       /* step T */                           \
        if (s == 0)                    /* early A write (aged) */             \
            *(__half*)((char*)(W) + wbA) = __float2half_rn(En1);              \
        ELEM(En1, In1, pB, En2, In2)   /* step T+1 */                         \
        if (s != 0)                    /* B write by the other lane */        \
            *(__half*)((char*)(W) + wbB) = __float2half_rn(En2);              \
        D1 = En1 - In1; D2 = En2 - In2;                                       \
        E = En2; I = In2;                                                     \
        asm volatile("s_barrier" ::: "memory");                               \
    }

__global__ __launch_bounds__(NT, 1)
void nmm_kernel(const float* __restrict__ params,
                const float* __restrict__ Cjk,
                const float* __restrict__ y0,
                float* __restrict__ out,
                const int num_steps)
{
#pragma clang fp contract(off)
    const int tid = threadIdx.x;
    const int j   = tid >> 1;    // node 0..67
    const int s   = tid & 1;     // K-half 0/1

    // interleaved f16 (A,B) buffers, ping-ponged per superstep
    __shared__ __align__(16) unsigned Pb0[BW], Pb1[BW];

    const float tau_e = params[0], tau_i = params[1];
    const float P1 = params[2], P2 = params[3], P3 = params[4];
    const float P4 = params[5], P5 = params[6], Pp = params[7];
    const float kE = params[8], kI = params[9];

    const float LOG2E = 1.4426950408889634f;
    const float kE2 = -1.3f * LOG2E, bE2 = (1.3f * 4.0f) * LOG2E;
    const float kI2 = -2.0f * LOG2E, bI2 = (2.0f * 3.7f) * LOG2E;
    const float s0E = 1.0f / (1.0f + expf(5.2f));
    const float s0I = 1.0f / (1.0f + expf(7.4f));
    const float inv_te = 1.0f / tau_e, inv_ti = 1.0f / tau_i;

    // C row j, K-chunk s -> 18 half2 words (s=1: pairs 16,17 are zero pad)
    const float* crow = Cjk + j * NN;
    const int k0 = s * 36;
    auto cp = [&](int m) -> unsigned {
        const int k = k0 + 2 * m;
        return (k + 1 < NN) ? packh2(crow[k], crow[k + 1]) : 0u;
    };
    const uint4 c0 = make_uint4(cp(0),  cp(1),  cp(2),  cp(3));
    const uint4 c1 = make_uint4(cp(4),  cp(5),  cp(6),  cp(7));
    const uint4 c2 = make_uint4(cp(8),  cp(9),  cp(10), cp(11));
    const uint4 c3 = make_uint4(cp(12), cp(13), cp(14), cp(15));
    const unsigned c4x = cp(16), c4y = cp(17);

    // init: reference steps 0 AND 1 both use C@E_0 -> A = B = E_0 pairs
    for (int idx = tid; idx < 2 * BW; idx += NT) {
        const int b  = (idx >= BW) ? 1 : 0;
        const int w  = idx - b * BW;
        const int si = w / 36, wl = w - si * 36, pl = wl >> 1;
        const int k  = si * 36 + 2 * pl;
        unsigned v = 0u;
        if (b == 0 && k + 1 < NN) v = packh2(y0[k], y0[k + 1]);
        (b ? Pb1 : Pb0)[w] = v;
    }

    // this node's write slots (byte offsets): A-word then B-word
    const int siW = (j >= 36) ? 1 : 0;
    const int kl  = j - siW * 36;
    const int wbA = (siW * 36 + 2 * (kl >> 1)) * 4 + (kl & 1) * 2;
    const int wbB = wbA + 4;

    float E = y0[j];
    float I = y0[NN + j];
    float* op = out + (size_t)j * (size_t)num_steps;

    // init barrier keeps the full waitcnt + memory clobber (one-time cost)
    asm volatile("s_waitcnt lgkmcnt(0)\ns_barrier" ::: "memory");

    int t = 0;
    for (; t + 3 < num_steps; t += 4) {
        float d0, d1, d2, d3;
        SUPER(Pb0, Pb1, d0, d1)
        SUPER(Pb1, Pb0, d2, d3)
        if (s == 0) *(float4*)(op + t) = make_float4(d0, d1, d2, d3);
    }
    // generic tails (dead for num_steps % 4 == 0, kept for correctness)
    bool rb1 = false;
    if (t + 1 < num_steps) {
        float d0, d1;
        SUPER(Pb0, Pb1, d0, d1)
        if (s == 0) *(float2*)(op + t) = make_float2(d0, d1);
        t += 2; rb1 = true;
    }
    if (t < num_steps) {   // final odd step: conn = C @ A-halves (E_{t-1})
        const unsigned* R = rb1 ? Pb1 : Pb0;
        const uint4* vp_ = (const uint4*)&R[s * 36];
        const uint4 u0 = vp_[0], u1 = vp_[1], u2 = vp_[2], u3 = vp_[3],
                    u4 = vp_[4], u5 = vp_[5], u6 = vp_[6], u7 = vp_[7],
                    u8 = vp_[8];
        float a0 = 0.f, a1 = 0.f, a2 = 0.f, a3 = 0.f;
#define MACL(c, uA, uB)                     \
        a0 = DOT2(c.x, uA.x, a0);           \
        a1 = DOT2(c.y, uA.z, a1);           \
        a2 = DOT2(c.z, uB.x, a2);           \
        a3 = DOT2(c.w, uB.z, a3);
        MACL(c0, u0, u1) MACL(c1, u2, u3) MACL(c2, u4, u5) MACL(c3, u6, u7)
        a0 = DOT2(c4x, u8.x, a0);
        a1 = DOT2(c4y, u8.z, a1);
#undef MACL
        float pA = (a0 + a1) + (a2 + a3);
        pA += dpp_xor1(pA);
        float En1, In1;
        ELEM(E, I, pA, En1, In1)
        if (s == 0) op[t] = En1 - In1;
    }
}

extern "C" void kernel_launch(void* const* d_in, const int* in_sizes, int n_in,
                              void* d_out, int out_size, void* d_ws, size_t ws_size,
                              hipStream_t stream) {
    const float* params = (const float*)d_in[0];
    const float* Cjk    = (const float*)d_in[1];
    const float* y0     = (const float*)d_in[2];
    const int num_steps = out_size / NN;

    nmm_kernel<<<dim3(1), dim3(NT), 0, stream>>>(
        params, Cjk, y0, (float*)d_out, num_steps);
}

// Round 17
// 30612.845 us; speedup vs baseline: 1.1474x; 1.0183x over previous
//
#include <hip/hip_runtime.h>
#include <hip/hip_fp16.h>
#include <cmath>

#define NN 68     // nodes
#define NT 136    // 2 threads per node (K-split), 3 waves
#define BW 72     // words per buffer: 2 chunks x 18 pairs x 2 (A,B interleaved)

typedef _Float16 h2 __attribute__((ext_vector_type(2)));
__device__ __forceinline__ h2 as_h2(unsigned u) {
    return __builtin_bit_cast(h2, u);
}

// lane XOR 1 within quad via DPP quad_perm [1,0,3,2] -- pure VALU, no LDS
__device__ __forceinline__ float dpp_xor1(float x) {
    return __int_as_float(
        __builtin_amdgcn_mov_dpp(__float_as_int(x), 0xB1, 0xF, 0xF, true));
}

#if __has_builtin(__builtin_amdgcn_exp2f)
#define FAST_EXP2(x) __builtin_amdgcn_exp2f(x)
#else
#define FAST_EXP2(x) exp2f(x)
#endif
#define FAST_RCP(x) __builtin_amdgcn_rcpf(x)

#if __has_builtin(__builtin_amdgcn_fdot2)
#define DOT2(c, e, acc) __builtin_amdgcn_fdot2(as_h2(c), as_h2(e), (acc), false)
#else
__device__ __forceinline__ float dot2_sw(unsigned c, unsigned e, float acc) {
    h2 ch = as_h2(c), eh = as_h2(e);
    acc = fmaf((float)ch.x, (float)eh.x, acc);
    return fmaf((float)ch.y, (float)eh.y, acc);
}
#define DOT2(c, e, acc) dot2_sw(c, e, acc)
#endif

__device__ __forceinline__ unsigned packh2(float a, float b) {
    __half2 h = __floats2half2_rn(a, b);   // RNE
    return *reinterpret_cast<unsigned*>(&h);
}

// Interleaved layout: word 2p = A-pair(k=2p), word 2p+1 = B-pair(k=2p).
#define MAC8(c, uA, uB)                          \
    a0 = DOT2(c.x, uA.x, a0); b0 = DOT2(c.x, uA.y, b0); \
    a1 = DOT2(c.y, uA.z, a1); b1 = DOT2(c.y, uA.w, b1); \
    a2 = DOT2(c.z, uB.x, a2); b2 = DOT2(c.z, uB.y, b2); \
    a3 = DOT2(c.w, uB.z, a3); b3 = DOT2(c.w, uB.w, b3);

// one Euler sub-step (R4-validated fast exp2/rcp math, hand-fma'd)
#define ELEM(Ein, Iin, CONN, Eout, Iout)                                      \
    {                                                                         \
        const float xE = fmaf(P5, (CONN),                                     \
                              fmaf(P1, (Ein), fmaf(-P2, (Iin), Pp)));         \
        const float Se = FAST_RCP(1.0f + FAST_EXP2(fmaf(kE2, xE, bE2))) - s0E;\
        const float xI = fmaf(P3, (Ein), -(P4 * (Iin)));                      \
        const float Si = FAST_RCP(1.0f + FAST_EXP2(fmaf(kI2, xI, bI2))) - s0I;\
        Eout = fmaf(fmaf(kE - (Ein), Se, -(Ein)), inv_te, (Ein));             \
        Iout = fmaf(fmaf(kI - (Iin), Si, -(Iin)), inv_ti, (Iin));             \
    }

// R17 barrier: the INTRINSIC, not asm-with-"memory"-clobber. Convergent HW
// barrier with NO full memory clobber -> LICM may hoist params loads and
// the f32->f16 C-packing out of the loop (the ~150 cy/superstep the R14/R15
// attempts targeted). Per-thread LDS store->load order survives via alias
// analysis; cross-wave order is the HW barrier (no-waitcnt already
// validated bit-stable in R13). absmax != 0.0009765625 falsifies safety.
#define BARRIER() __builtin_amdgcn_s_barrier()

// SUPERSTEP: steps T, T+1, ONE barrier, NO pre-barrier waitcnt (R13,
// validated bit-identical). Early En1 write ages the write before the
// race window. 9 ds_read_b128, 36 v_dot2.
#define SUPER(R, W, D1, D2)                                                   \
    {                                                                         \
        const uint4* vp_ = (const uint4*)&(R)[s * 36];                        \
        const uint4 u0 = vp_[0], u1 = vp_[1], u2 = vp_[2], u3 = vp_[3],       \
                    u4 = vp_[4], u5 = vp_[5], u6 = vp_[6], u7 = vp_[7],       \
                    u8 = vp_[8];                                              \
        float a0=0.f,a1=0.f,a2=0.f,a3=0.f,b0=0.f,b1=0.f,b2=0.f,b3=0.f;        \
        MAC8(c0, u0, u1) MAC8(c1, u2, u3)                                     \
        MAC8(c2, u4, u5) MAC8(c3, u6, u7)                                     \
        a0 = DOT2(c4x, u8.x, a0); b0 = DOT2(c4x, u8.y, b0);                   \
        a1 = DOT2(c4y, u8.z, a1); b1 = DOT2(c4y, u8.w, b1);                   \
        float pA = (a0 + a1) + (a2 + a3);                                     \
        float pB = (b0 + b1) + (b2 + b3);                                     \
        pA += dpp_xor1(pA);            /* both K-lanes: full dot */           \
        pB += dpp_xor1(pB);                                                   \
        float En1, In1, En2, In2;                                             \
        ELEM(E, I, pA, En1, In1)       /* step T */                           \
        *(__half*)((char*)(W) + wbA) = __float2half_rn(En1);  /* early */     \
        ELEM(En1, In1, pB, En2, In2)   /* step T+1 */                         \
        *(__half*)((char*)(W) + wbB) = __float2half_rn(En2);                  \
        D1 = En1 - In1; D2 = En2 - In2;                                       \
        E = En2; I = In2;                                                     \
        BARRIER();                                                            \
    }

__global__ __launch_bounds__(NT, 1)
void nmm_kernel(const float* __restrict__ params,
                const float* __restrict__ Cjk,
                const float* __restrict__ y0,
                float* __restrict__ out,
                const int num_steps)
{
#pragma clang fp contract(off)
    const int tid = threadIdx.x;
    const int j   = tid >> 1;    // node 0..67
    const int s   = tid & 1;     // K-half 0/1

    // interleaved f16 (A,B) buffers, ping-ponged per superstep
    __shared__ __align__(16) unsigned Pb0[BW], Pb1[BW];

    const float tau_e = params[0], tau_i = params[1];
    const float P1 = params[2], P2 = params[3], P3 = params[4];
    const float P4 = params[5], P5 = params[6], Pp = params[7];
    const float kE = params[8], kI = params[9];

    const float LOG2E = 1.4426950408889634f;
    const float kE2 = -1.3f * LOG2E, bE2 = (1.3f * 4.0f) * LOG2E;
    const float kI2 = -2.0f * LOG2E, bI2 = (2.0f * 3.7f) * LOG2E;
    const float s0E = 1.0f / (1.0f + expf(5.2f));
    const float s0I = 1.0f / (1.0f + expf(7.4f));
    const float inv_te = 1.0f / tau_e, inv_ti = 1.0f / tau_i;

    // C row j, K-chunk s -> 18 half2 words (s=1: pairs 16,17 are zero pad)
    const float* crow = Cjk + j * NN;
    const int k0 = s * 36;
    auto cp = [&](int m) -> unsigned {
        const int k = k0 + 2 * m;
        return (k + 1 < NN) ? packh2(crow[k], crow[k + 1]) : 0u;
    };
    const uint4 c0 = make_uint4(cp(0),  cp(1),  cp(2),  cp(3));
    const uint4 c1 = make_uint4(cp(4),  cp(5),  cp(6),  cp(7));
    const uint4 c2 = make_uint4(cp(8),  cp(9),  cp(10), cp(11));
    const uint4 c3 = make_uint4(cp(12), cp(13), cp(14), cp(15));
    const unsigned c4x = cp(16), c4y = cp(17);

    // init: reference steps 0 AND 1 both use C@E_0 -> A = B = E_0 pairs
    for (int idx = tid; idx < 2 * BW; idx += NT) {
        const int b  = (idx >= BW) ? 1 : 0;
        const int w  = idx - b * BW;
        const int si = w / 36, wl = w - si * 36, pl = wl >> 1;
        const int k  = si * 36 + 2 * pl;
        unsigned v = 0u;
        if (b == 0 && k + 1 < NN) v = packh2(y0[k], y0[k + 1]);
        (b ? Pb1 : Pb0)[w] = v;
    }

    // this node's write slots (byte offsets): A-word then B-word
    const int siW = (j >= 36) ? 1 : 0;
    const int kl  = j - siW * 36;
    const int wbA = (siW * 36 + 2 * (kl >> 1)) * 4 + (kl & 1) * 2;
    const int wbB = wbA + 4;

    float E = y0[j];
    float I = y0[NN + j];
    float* op = out + (size_t)j * (size_t)num_steps;

    // init barrier keeps the full waitcnt + memory clobber (one-time cost)
    asm volatile("s_waitcnt lgkmcnt(0)\ns_barrier" ::: "memory");

    int t = 0;
    for (; t + 3 < num_steps; t += 4) {
        float d0, d1, d2, d3;
        SUPER(Pb0, Pb1, d0, d1)
        SUPER(Pb1, Pb0, d2, d3)
        if (s == 0) *(float4*)(op + t) = make_float4(d0, d1, d2, d3);
    }
    // generic tails (dead for num_steps % 4 == 0, kept for correctness)
    bool rb1 = false;
    if (t + 1 < num_steps) {
        float d0, d1;
        SUPER(Pb0, Pb1, d0, d1)
        if (s == 0) *(float2*)(op + t) = make_float2(d0, d1);
        t += 2; rb1 = true;
    }
    if (t < num_steps) {   // final odd step: conn = C @ A-halves (E_{t-1})
        const unsigned* R = rb1 ? Pb1 : Pb0;
        const uint4* vp_ = (const uint4*)&R[s * 36];
        const uint4 u0 = vp_[0], u1 = vp_[1], u2 = vp_[2], u3 = vp_[3],
                    u4 = vp_[4], u5 = vp_[5], u6 = vp_[6], u7 = vp_[7],
                    u8 = vp_[8];
        float a0 = 0.f, a1 = 0.f, a2 = 0.f, a3 = 0.f;
#define MACL(c, uA, uB)                     \
        a0 = DOT2(c.x, uA.x, a0);           \
        a1 = DOT2(c.y, uA.z, a1);           \
        a2 = DOT2(c.z, uB.x, a2);           \
        a3 = DOT2(c.w, uB.z, a3);
        MACL(c0, u0, u1) MACL(c1, u2, u3) MACL(c2, u4, u5) MACL(c3, u6, u7)
        a0 = DOT2(c4x, u8.x, a0);
        a1 = DOT2(c4y, u8.z, a1);
#undef MACL
        float pA = (a0 + a1) + (a2 + a3);
        pA += dpp_xor1(pA);
        float En1, In1;
        ELEM(E, I, pA, En1, In1)
        if (s == 0) op[t] = En1 - In1;
    }
}

extern "C" void kernel_launch(void* const* d_in, const int* in_sizes, int n_in,
                              void* d_out, int out_size, void* d_ws, size_t ws_size,
                              hipStream_t stream) {
    const float* params = (const float*)d_in[0];
    const float* Cjk    = (const float*)d_in[1];
    const float* y0     = (const float*)d_in[2];
    const int num_steps = out_size / NN;

    nmm_kernel<<<dim3(1), dim3(NT), 0, stream>>>(
        params, Cjk, y0, (float*)d_out, num_steps);
}